// Round 1
// baseline (719.439 us; speedup 1.0000x reference)
//
#include <hip/hip_runtime.h>
#include <math.h>

#define N_NODES 51200
#define N_EDGES 614400
#define N_GRAPHS 256
#define T_CAPS 8
#define D_DIM 128
#define BN_EPS 1e-5f

__device__ inline float waveReduceSum(float v) {
#pragma unroll
  for (int off = 1; off < 64; off <<= 1) v += __shfl_xor(v, off, 64);
  return v;
}

// ---- BatchNorm column stats: sum and sumsq per feature d ----
__global__ void bn_stats(const float* __restrict__ x, float* __restrict__ colsum,
                         float* __restrict__ colsq) {
  int d = threadIdx.x & 127;
  int h = threadIdx.x >> 7;
  float s = 0.f, s2 = 0.f;
  for (int n = blockIdx.x * 2 + h; n < N_NODES; n += gridDim.x * 2) {
    float v = x[n * D_DIM + d];
    s += v;
    s2 += v * v;
  }
  __shared__ float ls[256], ls2[256];
  ls[threadIdx.x] = s;
  ls2[threadIdx.x] = s2;
  __syncthreads();
  if (h == 0) {
    atomicAdd(&colsum[d], ls[d] + ls[d + 128]);
    atomicAdd(&colsq[d], ls2[d] + ls2[d + 128]);
  }
}

__global__ void hist_cnt(const int* __restrict__ batch, int* __restrict__ cnt) {
  int n = blockIdx.x * blockDim.x + threadIdx.x;
  if (n < N_NODES) atomicAdd(&cnt[batch[n]], 1);
}

__global__ void hist_deg(const int* __restrict__ col, const float* __restrict__ ew,
                         float* __restrict__ deg) {
  int e = blockIdx.x * blockDim.x + threadIdx.x;
  if (e < N_EDGES) atomicAdd(&deg[col[e]], ew[e]);
}

__global__ void finalize_bn(const float* __restrict__ colsum, const float* __restrict__ colsq,
                            const float* __restrict__ gamma, const float* __restrict__ beta,
                            float* __restrict__ scale, float* __restrict__ shift) {
  int d = threadIdx.x;
  float mu = colsum[d] * (1.0f / N_NODES);
  float var = colsq[d] * (1.0f / N_NODES) - mu * mu;
  float rstd = rsqrtf(var + BN_EPS);
  float sc = gamma[d] * rstd;
  scale[d] = sc;
  shift[d] = beta[d] - mu * sc;
}

// exclusive scan of graph sizes -> start offsets (batch is sorted)
__global__ void scan_cnt(const int* __restrict__ cnt, int* __restrict__ start) {
  __shared__ int ls[N_GRAPHS];
  int g = threadIdx.x;
  ls[g] = cnt[g];
  __syncthreads();
  for (int off = 1; off < N_GRAPHS; off <<= 1) {
    int v = (g >= off) ? ls[g - off] : 0;
    __syncthreads();
    ls[g] += v;
    __syncthreads();
  }
  start[g] = ls[g] - cnt[g];
}

__global__ void compute_dis(const float* __restrict__ deg, float* __restrict__ dis) {
  int n = blockIdx.x * blockDim.x + threadIdx.x;
  if (n < N_NODES) {
    float dv = deg[n] + 1.0f;  // + self-loop weight
    dis[n] = dv > 0.f ? rsqrtf(fmaxf(dv, 1e-12f)) : 0.f;
  }
}

// agg[n,:] initialized with the self-loop term: dis[n]^2 * x_norm[n,:]
__global__ void self_agg(const float* __restrict__ x, const float* __restrict__ dis,
                         const float* __restrict__ scale, const float* __restrict__ shift,
                         float* __restrict__ agg) {
  int idx = blockIdx.x * blockDim.x + threadIdx.x;
  if (idx < N_NODES * D_DIM) {
    int n = idx >> 7, d = idx & 127;
    float di = dis[n];
    agg[idx] = di * di * (x[idx] * scale[d] + shift[d]);
  }
}

// scatter: agg[col,:] += dis[row]*w*dis[col] * x_norm[row,:]
__global__ void edge_scatter(const float* __restrict__ x, const int* __restrict__ row,
                             const int* __restrict__ col, const float* __restrict__ ew,
                             const float* __restrict__ dis,
                             const float* __restrict__ scale, const float* __restrict__ shift,
                             float* __restrict__ agg) {
  int e = blockIdx.x * 2 + (threadIdx.x >> 7);
  int d = threadIdx.x & 127;
  if (e < N_EDGES) {
    int r = row[e], c = col[e];
    float coef = dis[r] * ew[e] * dis[c];
    float v = coef * (x[r * D_DIM + d] * scale[d] + shift[d]);
    atomicAdd(&agg[c * D_DIM + d], v);
  }
}

// per-graph: aggsum[g,:] = sum of agg rows; xsum[g,:] = sum of x_norm rows
__global__ void graph_sums(const float* __restrict__ agg, const float* __restrict__ x,
                           const float* __restrict__ scale, const float* __restrict__ shift,
                           const int* __restrict__ start, const int* __restrict__ cnt,
                           float* __restrict__ aggsum, float* __restrict__ xsum) {
  int g = blockIdx.x;
  int d = threadIdx.x & 127, h = threadIdx.x >> 7;
  int st = start[g], c = cnt[g];
  float sa = 0.f, sx = 0.f;
  for (int n = st + h; n < st + c; n += 2) {
    sa += agg[n * D_DIM + d];
    sx += x[n * D_DIM + d];
  }
  __shared__ float la[256], lx[256];
  la[threadIdx.x] = sa;
  lx[threadIdx.x] = sx;
  __syncthreads();
  if (h == 0) {
    aggsum[g * D_DIM + d] = la[d] + la[d + 128];
    xsum[g * D_DIM + d] = scale[d] * (lx[d] + lx[d + 128]) + (float)c * shift[d];
  }
}

// Per (g,t): s = p@W[t] + coef*bias[t] [+ x_mean]; v=squash(s);
// MODE 1: p=aggsum, coef=cnt, s*=1/8 (uniform c). outputs wv,bv
// MODE 2: p=ac[g,t], coef=csum.            outputs wv,bv
// MODE 3: p=ac[g,t], coef=csum, + x_mean.  outputs |v| to out
template <int MODE>
__global__ void capsule_step(const float* __restrict__ W, const float* __restrict__ bias,
                             const float* __restrict__ aggsum, const float* __restrict__ ac,
                             const float* __restrict__ csum, const int* __restrict__ cnt,
                             const float* __restrict__ xsum, float* __restrict__ wv,
                             float* __restrict__ bv, float* __restrict__ out) {
  int g = blockIdx.x >> 3, t = blockIdx.x & 7;
  int o = threadIdx.x;
  __shared__ float p[D_DIM];
  __shared__ float vsh[D_DIM];
  __shared__ float wred[2];
  if (MODE == 1)
    p[o] = aggsum[g * D_DIM + o];
  else
    p[o] = ac[(g * T_CAPS + t) * D_DIM + o];
  __syncthreads();
  const float* Wt = W + t * D_DIM * D_DIM;
  float s = 0.f;
#pragma unroll 8
  for (int dd = 0; dd < D_DIM; dd++) s += p[dd] * Wt[dd * D_DIM + o];
  float bterm = (MODE == 1) ? (float)cnt[g] : csum[g * T_CAPS + t];
  s += bterm * bias[t * D_DIM + o];
  if (MODE == 1) s *= 0.125f;
  if (MODE == 3) {
    float ic = 1.0f / fmaxf((float)cnt[g], 1.0f);
    s += xsum[g * D_DIM + o] * ic;
  }
  float ws = waveReduceSum(s * s);
  if ((threadIdx.x & 63) == 0) wred[threadIdx.x >> 6] = ws;
  __syncthreads();
  float s2 = wred[0] + wred[1];
  float f = (s2 / (1.0f + s2)) * rsqrtf(s2 + 1e-16f);
  if (MODE == 3) {
    if (o == 0) out[g * T_CAPS + t] = sqrtf(f * f * s2 + 1e-16f);
    return;
  }
  float v = f * s;
  vsh[o] = v;
  float bw = waveReduceSum(bias[t * D_DIM + o] * v);
  __syncthreads();  // vsh written; wred consumed
  if ((threadIdx.x & 63) == 0) wred[threadIdx.x >> 6] = bw;
  __syncthreads();
  if (o == 0) bv[g * T_CAPS + t] = wred[0] + wred[1];
  float acc = 0.f;
#pragma unroll 8
  for (int oo = 0; oo < D_DIM; oo++) acc += Wt[o * D_DIM + oo] * vsh[oo];
  wv[(g * T_CAPS + t) * D_DIM + o] = acc;
}

__device__ inline void flush_acc(float* __restrict__ ac, float* __restrict__ csum, int g,
                                 int lane, float* accLo, float* accHi, float* accC) {
#pragma unroll
  for (int t = 0; t < T_CAPS; t++) {
    atomicAdd(&ac[(g * T_CAPS + t) * D_DIM + lane], accLo[t]);
    atomicAdd(&ac[(g * T_CAPS + t) * D_DIM + 64 + lane], accHi[t]);
    accLo[t] = 0.f;
    accHi[t] = 0.f;
  }
  float cw = accC[0];
#pragma unroll
  for (int t = 1; t < T_CAPS; t++) cw = (lane == t) ? accC[t] : cw;
  if (lane < T_CAPS) atomicAdd(&csum[g * T_CAPS + lane], cw);
#pragma unroll
  for (int t = 0; t < T_CAPS; t++) accC[t] = 0.f;
}

// one wave per contiguous node chunk: b update + softmax + weighted-agg accumulation
template <int USE_PREV_B>
__global__ void node_pass(const float* __restrict__ agg, const int* __restrict__ batch,
                          const float* __restrict__ wv, const float* __restrict__ bv,
                          float* __restrict__ b, float* __restrict__ ac,
                          float* __restrict__ csum) {
  int wave = (blockIdx.x * blockDim.x + threadIdx.x) >> 6;
  int lane = threadIdx.x & 63;
  int nwaves = (gridDim.x * blockDim.x) >> 6;
  int chunk = (N_NODES + nwaves - 1) / nwaves;
  int n0 = wave * chunk;
  int n1 = min(N_NODES, n0 + chunk);
  if (n0 >= n1) return;
  float accLo[T_CAPS] = {0.f}, accHi[T_CAPS] = {0.f}, accC[T_CAPS] = {0.f};
  int gcur = batch[n0];
  for (int n = n0; n < n1; n++) {
    int g = batch[n];
    if (g != gcur) {
      flush_acc(ac, csum, gcur, lane, accLo, accHi, accC);
      gcur = g;
    }
    float alo = agg[n * D_DIM + lane];
    float ahi = agg[n * D_DIM + 64 + lane];
    const float* wvg = wv + g * T_CAPS * D_DIM;
    const float* bvg = bv + g * T_CAPS;
    float bnew[T_CAPS];
#pragma unroll
    for (int t = 0; t < T_CAPS; t++) {
      float pr = alo * wvg[t * D_DIM + lane] + ahi * wvg[t * D_DIM + 64 + lane];
      pr = waveReduceSum(pr);
      float dt = pr + bvg[t];
      bnew[t] = USE_PREV_B ? (b[n * T_CAPS + t] + dt) : dt;
    }
    // store b via lane-select chain (lanes 0..7 write t=lane)
    float bw = bnew[0];
#pragma unroll
    for (int t = 1; t < T_CAPS; t++) bw = (lane == t) ? bnew[t] : bw;
    if (lane < T_CAPS) b[n * T_CAPS + lane] = bw;
    // softmax over T
    float m = bnew[0];
#pragma unroll
    for (int t = 1; t < T_CAPS; t++) m = fmaxf(m, bnew[t]);
    float Z = 0.f, cc[T_CAPS];
#pragma unroll
    for (int t = 0; t < T_CAPS; t++) {
      cc[t] = __expf(bnew[t] - m);
      Z += cc[t];
    }
    float iz = 1.0f / Z;
#pragma unroll
    for (int t = 0; t < T_CAPS; t++) {
      float c = cc[t] * iz;
      accLo[t] += c * alo;
      accHi[t] += c * ahi;
      accC[t] += c;
    }
  }
  flush_acc(ac, csum, gcur, lane, accLo, accHi, accC);
}

extern "C" void kernel_launch(void* const* d_in, const int* in_sizes, int n_in, void* d_out,
                              int out_size, void* d_ws, size_t ws_size, hipStream_t stream) {
  const float* x = (const float*)d_in[0];
  const float* ew = (const float*)d_in[1];
  const float* gamma = (const float*)d_in[2];
  const float* beta = (const float*)d_in[3];
  const float* W = (const float*)d_in[4];
  const float* bias = (const float*)d_in[5];
  const int* eidx = (const int*)d_in[6];
  const int* batch = (const int*)d_in[7];
  float* out = (float*)d_out;
  float* w = (float*)d_ws;

  const int* row = eidx;
  const int* col = eidx + N_EDGES;

  float* colsum = w + 0;
  float* colsq = w + 128;
  float* scale = w + 256;
  float* shift = w + 384;
  float* deg = w + 512;
  float* dis = deg + N_NODES;
  float* agg = dis + N_NODES;
  float* b = agg + (size_t)N_NODES * D_DIM;
  float* aggsum = b + N_NODES * T_CAPS;
  float* xsum = aggsum + N_GRAPHS * D_DIM;
  float* wv = xsum + N_GRAPHS * D_DIM;
  float* bv = wv + N_GRAPHS * T_CAPS * D_DIM;
  float* ac = bv + N_GRAPHS * T_CAPS;
  float* csum = ac + N_GRAPHS * T_CAPS * D_DIM;
  int* cnt = (int*)(csum + N_GRAPHS * T_CAPS);
  int* start = cnt + N_GRAPHS;

  hipMemsetAsync(w, 0, (512 + N_NODES) * sizeof(float), stream);  // colsum/colsq/scale/shift/deg
  hipMemsetAsync(cnt, 0, N_GRAPHS * sizeof(int), stream);

  bn_stats<<<512, 256, 0, stream>>>(x, colsum, colsq);
  hist_cnt<<<(N_NODES + 255) / 256, 256, 0, stream>>>(batch, cnt);
  hist_deg<<<(N_EDGES + 255) / 256, 256, 0, stream>>>(col, ew, deg);
  finalize_bn<<<1, 128, 0, stream>>>(colsum, colsq, gamma, beta, scale, shift);
  scan_cnt<<<1, N_GRAPHS, 0, stream>>>(cnt, start);
  compute_dis<<<(N_NODES + 255) / 256, 256, 0, stream>>>(deg, dis);
  self_agg<<<(N_NODES * D_DIM) / 256, 256, 0, stream>>>(x, dis, scale, shift, agg);
  edge_scatter<<<N_EDGES / 2, 256, 0, stream>>>(x, row, col, ew, dis, scale, shift, agg);
  graph_sums<<<N_GRAPHS, 256, 0, stream>>>(agg, x, scale, shift, start, cnt, aggsum, xsum);

  // routing iter 1 (c uniform = 1/8; node_deg init cancels in softmax)
  capsule_step<1><<<N_GRAPHS * T_CAPS, 128, 0, stream>>>(W, bias, aggsum, ac, csum, cnt, xsum,
                                                         wv, bv, out);
  hipMemsetAsync(ac, 0, (N_GRAPHS * T_CAPS * D_DIM + N_GRAPHS * T_CAPS) * sizeof(float), stream);
  node_pass<0><<<400, 256, 0, stream>>>(agg, batch, wv, bv, b, ac, csum);
  // routing iter 2
  capsule_step<2><<<N_GRAPHS * T_CAPS, 128, 0, stream>>>(W, bias, aggsum, ac, csum, cnt, xsum,
                                                         wv, bv, out);
  hipMemsetAsync(ac, 0, (N_GRAPHS * T_CAPS * D_DIM + N_GRAPHS * T_CAPS) * sizeof(float), stream);
  node_pass<1><<<400, 256, 0, stream>>>(agg, batch, wv, bv, b, ac, csum);
  // final
  capsule_step<3><<<N_GRAPHS * T_CAPS, 128, 0, stream>>>(W, bias, aggsum, ac, csum, cnt, xsum,
                                                         wv, bv, out);
}

// Round 2
// 568.830 us; speedup vs baseline: 1.2648x; 1.2648x over previous
//
#include <hip/hip_runtime.h>
#include <math.h>

#define N_NODES 51200
#define N_EDGES 614400
#define N_GRAPHS 256
#define T_CAPS 8
#define D_DIM 128
#define BN_EPS 1e-5f

__device__ inline float waveReduceSum(float v) {
#pragma unroll
  for (int off = 1; off < 64; off <<= 1) v += __shfl_xor(v, off, 64);
  return v;
}

// ---- BatchNorm column stats: sum and sumsq per feature d ----
__global__ void bn_stats(const float* __restrict__ x, float* __restrict__ colsum,
                         float* __restrict__ colsq) {
  int d = threadIdx.x & 127;
  int h = threadIdx.x >> 7;
  float s = 0.f, s2 = 0.f;
  for (int n = blockIdx.x * 2 + h; n < N_NODES; n += gridDim.x * 2) {
    float v = x[n * D_DIM + d];
    s += v;
    s2 += v * v;
  }
  __shared__ float ls[256], ls2[256];
  ls[threadIdx.x] = s;
  ls2[threadIdx.x] = s2;
  __syncthreads();
  if (h == 0) {
    atomicAdd(&colsum[d], ls[d] + ls[d + 128]);
    atomicAdd(&colsq[d], ls2[d] + ls2[d + 128]);
  }
}

__global__ void hist_cnt(const int* __restrict__ batch, int* __restrict__ cnt) {
  int n = blockIdx.x * blockDim.x + threadIdx.x;
  if (n < N_NODES) atomicAdd(&cnt[batch[n]], 1);
}

// per-edge: weighted degree (float) + integer in-degree histogram
__global__ void edge_hist(const int* __restrict__ col, const float* __restrict__ ew,
                          float* __restrict__ deg, int* __restrict__ cnt_in) {
  int e = blockIdx.x * blockDim.x + threadIdx.x;
  if (e < N_EDGES) {
    int c = col[e];
    atomicAdd(&deg[c], ew[e]);
    atomicAdd(&cnt_in[c], 1);
  }
}

__global__ void finalize_bn(const float* __restrict__ colsum, const float* __restrict__ colsq,
                            const float* __restrict__ gamma, const float* __restrict__ beta,
                            float* __restrict__ scale, float* __restrict__ shift) {
  int d = threadIdx.x;
  float mu = colsum[d] * (1.0f / N_NODES);
  float var = colsq[d] * (1.0f / N_NODES) - mu * mu;
  float rstd = rsqrtf(var + BN_EPS);
  float sc = gamma[d] * rstd;
  scale[d] = sc;
  shift[d] = beta[d] - mu * sc;
}

// exclusive scan of graph sizes -> start offsets (batch is sorted)
__global__ void scan_cnt(const int* __restrict__ cnt, int* __restrict__ start) {
  __shared__ int ls[N_GRAPHS];
  int g = threadIdx.x;
  ls[g] = cnt[g];
  __syncthreads();
  for (int off = 1; off < N_GRAPHS; off <<= 1) {
    int v = (g >= off) ? ls[g - off] : 0;
    __syncthreads();
    ls[g] += v;
    __syncthreads();
  }
  start[g] = ls[g] - cnt[g];
}

// exclusive scan of per-node in-degree -> CSR row starts. N = 1024*50 exactly.
__global__ void scan_nodes(const int* __restrict__ cnt_in, int* __restrict__ node_start) {
  __shared__ int ls[1024];
  int t = threadIdx.x;
  int base = t * 50;
  int s = 0;
#pragma unroll 10
  for (int i = 0; i < 50; i++) s += cnt_in[base + i];
  ls[t] = s;
  __syncthreads();
  for (int off = 1; off < 1024; off <<= 1) {
    int v = (t >= off) ? ls[t - off] : 0;
    __syncthreads();
    ls[t] += v;
    __syncthreads();
  }
  int run = t ? ls[t - 1] : 0;
  for (int i = 0; i < 50; i++) {
    node_start[base + i] = run;
    run += cnt_in[base + i];
  }
}

__global__ void compute_dis(const float* __restrict__ deg, float* __restrict__ dis) {
  int n = blockIdx.x * blockDim.x + threadIdx.x;
  if (n < N_NODES) {
    float dv = deg[n] + 1.0f;  // + self-loop weight
    dis[n] = dv > 0.f ? rsqrtf(fmaxf(dv, 1e-12f)) : 0.f;
  }
}

// bucket edges by destination: csr_row[slot]=src, csr_w[slot]=dis[src]*ew
__global__ void fill_csr(const int* __restrict__ row, const int* __restrict__ col,
                         const float* __restrict__ ew, const float* __restrict__ dis,
                         const int* __restrict__ node_start, int* __restrict__ cursor,
                         int* __restrict__ csr_row, float* __restrict__ csr_w) {
  int e = blockIdx.x * blockDim.x + threadIdx.x;
  if (e < N_EDGES) {
    int c = col[e], r = row[e];
    int slot = node_start[c] + atomicAdd(&cursor[c], 1);
    csr_row[slot] = r;
    csr_w[slot] = dis[r] * ew[e];
  }
}

// one wave per node: agg[n] = dis[n] * sum_e csr_w[e]*xhat[src_e] + dis[n]^2 * xhat[n]
__global__ void node_gather(const float* __restrict__ x, const float* __restrict__ scale,
                            const float* __restrict__ shift, const float* __restrict__ dis,
                            const int* __restrict__ node_start, const int* __restrict__ cnt_in,
                            const int* __restrict__ csr_row, const float* __restrict__ csr_w,
                            float* __restrict__ agg) {
  int n = blockIdx.x * 4 + (threadIdx.x >> 6);
  int lane = threadIdx.x & 63;
  const float2* x2 = (const float2*)x;
  float2 scv = ((const float2*)scale)[lane];
  float2 shv = ((const float2*)shift)[lane];
  int st = node_start[n], c = cnt_in[n];
  float a0 = 0.f, a1 = 0.f;
  for (int base = 0; base < c; base += 64) {
    int k = base + lane;
    int r = (k < c) ? csr_row[st + k] : 0;
    float wc = (k < c) ? csr_w[st + k] : 0.f;
    int m = min(64, c - base);
    for (int j = 0; j < m; j++) {
      int rj = __shfl(r, j, 64);
      float wj = __shfl(wc, j, 64);
      float2 xv = x2[rj * 64 + lane];
      a0 += wj * (xv.x * scv.x + shv.x);
      a1 += wj * (xv.y * scv.y + shv.y);
    }
  }
  float di = dis[n];
  float2 xs = x2[n * 64 + lane];
  float2 o;
  o.x = di * a0 + di * di * (xs.x * scv.x + shv.x);
  o.y = di * a1 + di * di * (xs.y * scv.y + shv.y);
  ((float2*)agg)[n * 64 + lane] = o;
}

// per-graph: aggsum[g,:] = sum of agg rows; xsum[g,:] = sum of x_norm rows
__global__ void graph_sums(const float* __restrict__ agg, const float* __restrict__ x,
                           const float* __restrict__ scale, const float* __restrict__ shift,
                           const int* __restrict__ start, const int* __restrict__ cnt,
                           float* __restrict__ aggsum, float* __restrict__ xsum) {
  int g = blockIdx.x;
  int d = threadIdx.x & 127, h = threadIdx.x >> 7;
  int st = start[g], c = cnt[g];
  float sa = 0.f, sx = 0.f;
  for (int n = st + h; n < st + c; n += 2) {
    sa += agg[n * D_DIM + d];
    sx += x[n * D_DIM + d];
  }
  __shared__ float la[256], lx[256];
  la[threadIdx.x] = sa;
  lx[threadIdx.x] = sx;
  __syncthreads();
  if (h == 0) {
    aggsum[g * D_DIM + d] = la[d] + la[d + 128];
    xsum[g * D_DIM + d] = scale[d] * (lx[d] + lx[d + 128]) + (float)c * shift[d];
  }
}

// Per (g,t): s = p@W[t] + coef*bias[t] [+ x_mean]; v=squash(s);
// MODE 1: p=aggsum, coef=cnt, s*=1/8 (uniform c). outputs wv,bv
// MODE 2: p=ac[g,t], coef=csum.            outputs wv,bv
// MODE 3: p=ac[g,t], coef=csum, + x_mean.  outputs |v| to out
template <int MODE>
__global__ void capsule_step(const float* __restrict__ W, const float* __restrict__ bias,
                             const float* __restrict__ aggsum, const float* __restrict__ ac,
                             const float* __restrict__ csum, const int* __restrict__ cnt,
                             const float* __restrict__ xsum, float* __restrict__ wv,
                             float* __restrict__ bv, float* __restrict__ out) {
  int g = blockIdx.x >> 3, t = blockIdx.x & 7;
  int o = threadIdx.x;
  __shared__ float p[D_DIM];
  __shared__ float vsh[D_DIM];
  __shared__ float wred[2];
  if (MODE == 1)
    p[o] = aggsum[g * D_DIM + o];
  else
    p[o] = ac[(g * T_CAPS + t) * D_DIM + o];
  __syncthreads();
  const float* Wt = W + t * D_DIM * D_DIM;
  float s = 0.f;
#pragma unroll 8
  for (int dd = 0; dd < D_DIM; dd++) s += p[dd] * Wt[dd * D_DIM + o];
  float bterm = (MODE == 1) ? (float)cnt[g] : csum[g * T_CAPS + t];
  s += bterm * bias[t * D_DIM + o];
  if (MODE == 1) s *= 0.125f;
  if (MODE == 3) {
    float ic = 1.0f / fmaxf((float)cnt[g], 1.0f);
    s += xsum[g * D_DIM + o] * ic;
  }
  float ws = waveReduceSum(s * s);
  if ((threadIdx.x & 63) == 0) wred[threadIdx.x >> 6] = ws;
  __syncthreads();
  float s2 = wred[0] + wred[1];
  float f = (s2 / (1.0f + s2)) * rsqrtf(s2 + 1e-16f);
  if (MODE == 3) {
    if (o == 0) out[g * T_CAPS + t] = sqrtf(f * f * s2 + 1e-16f);
    return;
  }
  float v = f * s;
  vsh[o] = v;
  float bw = waveReduceSum(bias[t * D_DIM + o] * v);
  __syncthreads();  // vsh written; wred consumed
  if ((threadIdx.x & 63) == 0) wred[threadIdx.x >> 6] = bw;
  __syncthreads();
  if (o == 0) bv[g * T_CAPS + t] = wred[0] + wred[1];
  float acc = 0.f;
#pragma unroll 8
  for (int oo = 0; oo < D_DIM; oo++) acc += Wt[o * D_DIM + oo] * vsh[oo];
  wv[(g * T_CAPS + t) * D_DIM + o] = acc;
}

__device__ inline void flush_acc(float* __restrict__ ac, float* __restrict__ csum, int g,
                                 int lane, float* accLo, float* accHi, float* accC) {
#pragma unroll
  for (int t = 0; t < T_CAPS; t++) {
    atomicAdd(&ac[(g * T_CAPS + t) * D_DIM + lane], accLo[t]);
    atomicAdd(&ac[(g * T_CAPS + t) * D_DIM + 64 + lane], accHi[t]);
    accLo[t] = 0.f;
    accHi[t] = 0.f;
  }
  float cw = accC[0];
#pragma unroll
  for (int t = 1; t < T_CAPS; t++) cw = (lane == t) ? accC[t] : cw;
  if (lane < T_CAPS) atomicAdd(&csum[g * T_CAPS + lane], cw);
#pragma unroll
  for (int t = 0; t < T_CAPS; t++) accC[t] = 0.f;
}

// one wave per contiguous node chunk: b update + softmax + weighted-agg accumulation
template <int USE_PREV_B>
__global__ void node_pass(const float* __restrict__ agg, const int* __restrict__ batch,
                          const float* __restrict__ wv, const float* __restrict__ bv,
                          float* __restrict__ b, float* __restrict__ ac,
                          float* __restrict__ csum) {
  int wave = (blockIdx.x * blockDim.x + threadIdx.x) >> 6;
  int lane = threadIdx.x & 63;
  int nwaves = (gridDim.x * blockDim.x) >> 6;
  int chunk = (N_NODES + nwaves - 1) / nwaves;
  int n0 = wave * chunk;
  int n1 = min(N_NODES, n0 + chunk);
  if (n0 >= n1) return;
  float accLo[T_CAPS] = {0.f}, accHi[T_CAPS] = {0.f}, accC[T_CAPS] = {0.f};
  int gcur = batch[n0];
  for (int n = n0; n < n1; n++) {
    int g = batch[n];
    if (g != gcur) {
      flush_acc(ac, csum, gcur, lane, accLo, accHi, accC);
      gcur = g;
    }
    float alo = agg[n * D_DIM + lane];
    float ahi = agg[n * D_DIM + 64 + lane];
    const float* wvg = wv + g * T_CAPS * D_DIM;
    const float* bvg = bv + g * T_CAPS;
    float bnew[T_CAPS];
#pragma unroll
    for (int t = 0; t < T_CAPS; t++) {
      float pr = alo * wvg[t * D_DIM + lane] + ahi * wvg[t * D_DIM + 64 + lane];
      pr = waveReduceSum(pr);
      float dt = pr + bvg[t];
      bnew[t] = USE_PREV_B ? (b[n * T_CAPS + t] + dt) : dt;
    }
    // store b via lane-select chain (lanes 0..7 write t=lane)
    float bw = bnew[0];
#pragma unroll
    for (int t = 1; t < T_CAPS; t++) bw = (lane == t) ? bnew[t] : bw;
    if (lane < T_CAPS) b[n * T_CAPS + lane] = bw;
    // softmax over T
    float m = bnew[0];
#pragma unroll
    for (int t = 1; t < T_CAPS; t++) m = fmaxf(m, bnew[t]);
    float Z = 0.f, cc[T_CAPS];
#pragma unroll
    for (int t = 0; t < T_CAPS; t++) {
      cc[t] = __expf(bnew[t] - m);
      Z += cc[t];
    }
    float iz = 1.0f / Z;
#pragma unroll
    for (int t = 0; t < T_CAPS; t++) {
      float c = cc[t] * iz;
      accLo[t] += c * alo;
      accHi[t] += c * ahi;
      accC[t] += c;
    }
  }
  flush_acc(ac, csum, gcur, lane, accLo, accHi, accC);
}

extern "C" void kernel_launch(void* const* d_in, const int* in_sizes, int n_in, void* d_out,
                              int out_size, void* d_ws, size_t ws_size, hipStream_t stream) {
  const float* x = (const float*)d_in[0];
  const float* ew = (const float*)d_in[1];
  const float* gamma = (const float*)d_in[2];
  const float* beta = (const float*)d_in[3];
  const float* W = (const float*)d_in[4];
  const float* bias = (const float*)d_in[5];
  const int* eidx = (const int*)d_in[6];
  const int* batch = (const int*)d_in[7];
  float* out = (float*)d_out;
  float* w = (float*)d_ws;

  const int* row = eidx;
  const int* col = eidx + N_EDGES;

  float* colsum = w + 0;
  float* colsq = w + 128;
  float* scale = w + 256;
  float* shift = w + 384;
  float* deg = w + 512;
  float* dis = deg + N_NODES;
  float* agg = dis + N_NODES;
  float* b = agg + (size_t)N_NODES * D_DIM;
  float* aggsum = b + N_NODES * T_CAPS;
  float* xsum = aggsum + N_GRAPHS * D_DIM;
  float* wv = xsum + N_GRAPHS * D_DIM;
  float* bv = wv + N_GRAPHS * T_CAPS * D_DIM;
  float* ac = bv + N_GRAPHS * T_CAPS;
  float* csum = ac + N_GRAPHS * T_CAPS * D_DIM;
  float* csr_w = csum + N_GRAPHS * T_CAPS;
  int* csr_row = (int*)(csr_w + N_EDGES);
  int* cnt = csr_row + N_EDGES;
  int* start = cnt + N_GRAPHS;
  int* cnt_in = start + N_GRAPHS;
  int* cursor = cnt_in + N_NODES;
  int* node_start = cursor + N_NODES;

  hipMemsetAsync(w, 0, (512 + N_NODES) * sizeof(float), stream);  // stats + deg
  hipMemsetAsync(cnt, 0, (2 * N_GRAPHS + 2 * N_NODES) * sizeof(int), stream);  // cnt,start,cnt_in,cursor

  bn_stats<<<512, 256, 0, stream>>>(x, colsum, colsq);
  hist_cnt<<<(N_NODES + 255) / 256, 256, 0, stream>>>(batch, cnt);
  edge_hist<<<(N_EDGES + 255) / 256, 256, 0, stream>>>(col, ew, deg, cnt_in);
  finalize_bn<<<1, 128, 0, stream>>>(colsum, colsq, gamma, beta, scale, shift);
  scan_cnt<<<1, N_GRAPHS, 0, stream>>>(cnt, start);
  compute_dis<<<(N_NODES + 255) / 256, 256, 0, stream>>>(deg, dis);
  scan_nodes<<<1, 1024, 0, stream>>>(cnt_in, node_start);
  fill_csr<<<(N_EDGES + 255) / 256, 256, 0, stream>>>(row, col, ew, dis, node_start, cursor,
                                                      csr_row, csr_w);
  node_gather<<<N_NODES / 4, 256, 0, stream>>>(x, scale, shift, dis, node_start, cnt_in,
                                               csr_row, csr_w, agg);
  graph_sums<<<N_GRAPHS, 256, 0, stream>>>(agg, x, scale, shift, start, cnt, aggsum, xsum);

  // routing iter 1 (c uniform = 1/8; node_deg init cancels in softmax)
  capsule_step<1><<<N_GRAPHS * T_CAPS, 128, 0, stream>>>(W, bias, aggsum, ac, csum, cnt, xsum,
                                                         wv, bv, out);
  hipMemsetAsync(ac, 0, (N_GRAPHS * T_CAPS * D_DIM + N_GRAPHS * T_CAPS) * sizeof(float), stream);
  node_pass<0><<<1280, 256, 0, stream>>>(agg, batch, wv, bv, b, ac, csum);
  // routing iter 2
  capsule_step<2><<<N_GRAPHS * T_CAPS, 128, 0, stream>>>(W, bias, aggsum, ac, csum, cnt, xsum,
                                                         wv, bv, out);
  hipMemsetAsync(ac, 0, (N_GRAPHS * T_CAPS * D_DIM + N_GRAPHS * T_CAPS) * sizeof(float), stream);
  node_pass<1><<<1280, 256, 0, stream>>>(agg, batch, wv, bv, b, ac, csum);
  // final
  capsule_step<3><<<N_GRAPHS * T_CAPS, 128, 0, stream>>>(W, bias, aggsum, ac, csum, cnt, xsum,
                                                         wv, bv, out);
}

// Round 3
// 459.789 us; speedup vs baseline: 1.5647x; 1.2372x over previous
//
#include <hip/hip_runtime.h>
#include <math.h>

#define N_NODES 51200
#define N_EDGES 614400
#define N_GRAPHS 256
#define T_CAPS 8
#define D_DIM 128
#define BN_EPS 1e-5f

__device__ inline float waveReduceSum(float v) {
#pragma unroll
  for (int off = 1; off < 64; off <<= 1) v += __shfl_xor(v, off, 64);
  return v;
}

// ---- BatchNorm column stats: sum and sumsq per feature d ----
__global__ void bn_stats(const float* __restrict__ x, float* __restrict__ colsum,
                         float* __restrict__ colsq) {
  int d = threadIdx.x & 127;
  int h = threadIdx.x >> 7;
  float s = 0.f, s2 = 0.f;
  for (int n = blockIdx.x * 2 + h; n < N_NODES; n += gridDim.x * 2) {
    float v = x[n * D_DIM + d];
    s += v;
    s2 += v * v;
  }
  __shared__ float ls[256], ls2[256];
  ls[threadIdx.x] = s;
  ls2[threadIdx.x] = s2;
  __syncthreads();
  if (h == 0) {
    atomicAdd(&colsum[d], ls[d] + ls[d + 128]);
    atomicAdd(&colsq[d], ls2[d] + ls2[d + 128]);
  }
}

__global__ void hist_cnt(const int* __restrict__ batch, int* __restrict__ cnt) {
  int n = blockIdx.x * blockDim.x + threadIdx.x;
  if (n < N_NODES) atomicAdd(&cnt[batch[n]], 1);
}

// per-edge: weighted degree (float) + integer in-degree histogram
__global__ void edge_hist(const int* __restrict__ col, const float* __restrict__ ew,
                          float* __restrict__ deg, int* __restrict__ cnt_in) {
  int e = blockIdx.x * blockDim.x + threadIdx.x;
  if (e < N_EDGES) {
    int c = col[e];
    atomicAdd(&deg[c], ew[e]);
    atomicAdd(&cnt_in[c], 1);
  }
}

__global__ void finalize_bn(const float* __restrict__ colsum, const float* __restrict__ colsq,
                            const float* __restrict__ gamma, const float* __restrict__ beta,
                            float* __restrict__ scale, float* __restrict__ shift) {
  int d = threadIdx.x;
  float mu = colsum[d] * (1.0f / N_NODES);
  float var = colsq[d] * (1.0f / N_NODES) - mu * mu;
  float rstd = rsqrtf(var + BN_EPS);
  float sc = gamma[d] * rstd;
  scale[d] = sc;
  shift[d] = beta[d] - mu * sc;
}

// exclusive scan of graph sizes -> start offsets (batch is sorted)
__global__ void scan_cnt(const int* __restrict__ cnt, int* __restrict__ start) {
  __shared__ int ls[N_GRAPHS];
  int g = threadIdx.x;
  ls[g] = cnt[g];
  __syncthreads();
  for (int off = 1; off < N_GRAPHS; off <<= 1) {
    int v = (g >= off) ? ls[g - off] : 0;
    __syncthreads();
    ls[g] += v;
    __syncthreads();
  }
  start[g] = ls[g] - cnt[g];
}

// ---- 3-stage parallel scan of cnt_in (51200 = 200 x 256) ----
__global__ void scan_part(const int* __restrict__ cnt_in, int* __restrict__ bsum) {
  __shared__ int ls[256];
  int i = blockIdx.x * 256 + threadIdx.x;
  ls[threadIdx.x] = cnt_in[i];
  __syncthreads();
  for (int off = 128; off; off >>= 1) {
    if (threadIdx.x < off) ls[threadIdx.x] += ls[threadIdx.x + off];
    __syncthreads();
  }
  if (threadIdx.x == 0) bsum[blockIdx.x] = ls[0];
}

__global__ void scan_off(const int* __restrict__ bsum, int* __restrict__ boff) {
  __shared__ int ls[256];
  int t = threadIdx.x;
  int v0 = (t < 200) ? bsum[t] : 0;
  ls[t] = v0;
  __syncthreads();
  for (int off = 1; off < 256; off <<= 1) {
    int v = (t >= off) ? ls[t - off] : 0;
    __syncthreads();
    ls[t] += v;
    __syncthreads();
  }
  if (t < 200) boff[t] = ls[t] - v0;
}

// finalize node_start (exclusive scan) and fuse dis = rsqrt(deg+1)
__global__ void scan_fin(const int* __restrict__ cnt_in, const int* __restrict__ boff,
                         const float* __restrict__ deg, int* __restrict__ node_start,
                         float* __restrict__ dis) {
  __shared__ int ls[256];
  int t = threadIdx.x;
  int idx = blockIdx.x * 256 + t;
  int v = cnt_in[idx];
  ls[t] = v;
  __syncthreads();
  for (int off = 1; off < 256; off <<= 1) {
    int u = (t >= off) ? ls[t - off] : 0;
    __syncthreads();
    ls[t] += u;
    __syncthreads();
  }
  node_start[idx] = boff[blockIdx.x] + ls[t] - v;
  float dv = deg[idx] + 1.0f;  // + self-loop weight
  dis[idx] = dv > 0.f ? rsqrtf(fmaxf(dv, 1e-12f)) : 0.f;
}

// bucket edges by destination: csr[slot] = (src, dis[src]*ew) as one 8B record
__global__ void fill_csr(const int* __restrict__ row, const int* __restrict__ col,
                         const float* __restrict__ ew, const float* __restrict__ dis,
                         const int* __restrict__ node_start, int* __restrict__ cursor,
                         int2* __restrict__ csr) {
  int e = blockIdx.x * blockDim.x + threadIdx.x;
  if (e < N_EDGES) {
    int c = col[e], r = row[e];
    int slot = node_start[c] + atomicAdd(&cursor[c], 1);
    csr[slot] = make_int2(r, __float_as_int(dis[r] * ew[e]));
  }
}

// one wave per node: agg[n] = dis[n] * sum_e w_e*xhat[src_e] + dis[n]^2 * xhat[n]
__global__ void node_gather(const float* __restrict__ x, const float* __restrict__ scale,
                            const float* __restrict__ shift, const float* __restrict__ dis,
                            const int* __restrict__ node_start, const int* __restrict__ cnt_in,
                            const int2* __restrict__ csr, float* __restrict__ agg) {
  int n = blockIdx.x * 4 + (threadIdx.x >> 6);
  int lane = threadIdx.x & 63;
  const float2* x2 = (const float2*)x;
  float2 scv = ((const float2*)scale)[lane];
  float2 shv = ((const float2*)shift)[lane];
  int st = node_start[n], c = cnt_in[n];
  float a0 = 0.f, a1 = 0.f;
  int j = 0;
  for (; j + 4 <= c; j += 4) {
    int2 e0 = csr[st + j], e1 = csr[st + j + 1], e2 = csr[st + j + 2], e3 = csr[st + j + 3];
    float2 v0 = x2[e0.x * 64 + lane];
    float2 v1 = x2[e1.x * 64 + lane];
    float2 v2 = x2[e2.x * 64 + lane];
    float2 v3 = x2[e3.x * 64 + lane];
    float w0 = __int_as_float(e0.y), w1 = __int_as_float(e1.y);
    float w2 = __int_as_float(e2.y), w3 = __int_as_float(e3.y);
    a0 += w0 * (v0.x * scv.x + shv.x) + w1 * (v1.x * scv.x + shv.x) +
          w2 * (v2.x * scv.x + shv.x) + w3 * (v3.x * scv.x + shv.x);
    a1 += w0 * (v0.y * scv.y + shv.y) + w1 * (v1.y * scv.y + shv.y) +
          w2 * (v2.y * scv.y + shv.y) + w3 * (v3.y * scv.y + shv.y);
  }
  for (; j < c; j++) {
    int2 e = csr[st + j];
    float2 v = x2[e.x * 64 + lane];
    float w = __int_as_float(e.y);
    a0 += w * (v.x * scv.x + shv.x);
    a1 += w * (v.y * scv.y + shv.y);
  }
  float di = dis[n];
  float2 xs = x2[n * 64 + lane];
  float2 o;
  o.x = di * a0 + di * di * (xs.x * scv.x + shv.x);
  o.y = di * a1 + di * di * (xs.y * scv.y + shv.y);
  ((float2*)agg)[n * 64 + lane] = o;
}

// per-graph: aggsum[g,:] = sum of agg rows; xsum[g,:] = sum of x_norm rows
__global__ void graph_sums(const float* __restrict__ agg, const float* __restrict__ x,
                           const float* __restrict__ scale, const float* __restrict__ shift,
                           const int* __restrict__ start, const int* __restrict__ cnt,
                           float* __restrict__ aggsum, float* __restrict__ xsum) {
  int g = blockIdx.x;
  int d = threadIdx.x & 127, h = threadIdx.x >> 7;
  int st = start[g], c = cnt[g];
  float sa = 0.f, sx = 0.f;
  for (int n = st + h; n < st + c; n += 2) {
    sa += agg[n * D_DIM + d];
    sx += x[n * D_DIM + d];
  }
  __shared__ float la[256], lx[256];
  la[threadIdx.x] = sa;
  lx[threadIdx.x] = sx;
  __syncthreads();
  if (h == 0) {
    aggsum[g * D_DIM + d] = la[d] + la[d + 128];
    xsum[g * D_DIM + d] = scale[d] * (lx[d] + lx[d + 128]) + (float)c * shift[d];
  }
}

// Per (g,t): s = p@W[t] + coef*bias[t] [+ x_mean]; v=squash(s);
// MODE 1: p=aggsum, coef=cnt, s*=1/8 (uniform c). outputs wv,bv
// MODE 2: p=ac[g,t], coef=csum.            outputs wv,bv
// MODE 3: p=ac[g,t], coef=csum, + x_mean.  outputs |v| to out
template <int MODE>
__global__ void capsule_step(const float* __restrict__ W, const float* __restrict__ bias,
                             const float* __restrict__ aggsum, const float* __restrict__ ac,
                             const float* __restrict__ csum, const int* __restrict__ cnt,
                             const float* __restrict__ xsum, float* __restrict__ wv,
                             float* __restrict__ bv, float* __restrict__ out) {
  int g = blockIdx.x >> 3, t = blockIdx.x & 7;
  int o = threadIdx.x;
  __shared__ float p[D_DIM];
  __shared__ float vsh[D_DIM];
  __shared__ float wred[2];
  if (MODE == 1)
    p[o] = aggsum[g * D_DIM + o];
  else
    p[o] = ac[(g * T_CAPS + t) * D_DIM + o];
  __syncthreads();
  const float* Wt = W + t * D_DIM * D_DIM;
  float s = 0.f;
#pragma unroll 8
  for (int dd = 0; dd < D_DIM; dd++) s += p[dd] * Wt[dd * D_DIM + o];
  float bterm = (MODE == 1) ? (float)cnt[g] : csum[g * T_CAPS + t];
  s += bterm * bias[t * D_DIM + o];
  if (MODE == 1) s *= 0.125f;
  if (MODE == 3) {
    float ic = 1.0f / fmaxf((float)cnt[g], 1.0f);
    s += xsum[g * D_DIM + o] * ic;
  }
  float ws = waveReduceSum(s * s);
  if ((threadIdx.x & 63) == 0) wred[threadIdx.x >> 6] = ws;
  __syncthreads();
  float s2 = wred[0] + wred[1];
  float f = (s2 / (1.0f + s2)) * rsqrtf(s2 + 1e-16f);
  if (MODE == 3) {
    if (o == 0) out[g * T_CAPS + t] = sqrtf(f * f * s2 + 1e-16f);
    return;
  }
  float v = f * s;
  vsh[o] = v;
  float bw = waveReduceSum(bias[t * D_DIM + o] * v);
  __syncthreads();
  if ((threadIdx.x & 63) == 0) wred[threadIdx.x >> 6] = bw;
  __syncthreads();
  if (o == 0) bv[g * T_CAPS + t] = wred[0] + wred[1];
  float acc = 0.f;
#pragma unroll 8
  for (int oo = 0; oo < D_DIM; oo++) acc += Wt[o * D_DIM + oo] * vsh[oo];
  wv[(g * T_CAPS + t) * D_DIM + o] = acc;
}

// one block (256 thr) per graph: proj + b update + softmax + weighted accumulation.
// No cross-lane reductions, no atomics, deterministic ac/csum writes.
template <int USE_PREV_B>
__global__ void __launch_bounds__(256) node_pass2(
    const float* __restrict__ agg, const int* __restrict__ start, const int* __restrict__ cnt,
    const float* __restrict__ wv, const float* __restrict__ bv, float* __restrict__ b,
    float* __restrict__ ac, float* __restrict__ csum) {
  int g = blockIdx.x;
  int tid = threadIdx.x;
  __shared__ float wv_sh[T_CAPS][D_DIM];  // 4 KB
  __shared__ float bv_sh[T_CAPS];
  __shared__ float atile[32][132];        // 32 nodes x 128 (+4 pad) = 16.9 KB
  __shared__ float dtsh[32][9];           // logits (padded: stride 9 kills conflicts)
  __shared__ float csh[32][9];            // softmax coefficients

  for (int i = tid; i < T_CAPS * D_DIM; i += 256) wv_sh[0][i] = wv[g * T_CAPS * D_DIM + i];
  if (tid < T_CAPS) bv_sh[tid] = bv[g * T_CAPS + tid];

  int st = start[g], c = cnt[g];
  int nL = tid & 31, tL = tid >> 5;  // proj/softmax decomposition: (node, t)
  float4 acc = make_float4(0.f, 0.f, 0.f, 0.f);  // accum decomposition: (t=tL, d4=nL*4)
  int d4 = nL << 2;
  float csl = 0.f;  // running csum partial for slot (nL, tL)

  int ntiles = (c + 31) >> 5;
  for (int tile = 0; tile < ntiles; tile++) {
    int n0 = tile * 32;
    int nv = min(32, c - n0);
    __syncthreads();  // atile/csh safe to overwrite
    const float4* aggv = (const float4*)(agg + (size_t)(st + n0) * D_DIM);
    for (int i = tid; i < 32 * 32; i += 256) {
      float4 v = (i < nv * 32) ? aggv[i] : make_float4(0.f, 0.f, 0.f, 0.f);
      *(float4*)&atile[i >> 5][(i & 31) << 2] = v;
    }
    __syncthreads();
    // proj: thread (nL,tL) full 128-dot from LDS
    float pr = 0.f;
#pragma unroll 8
    for (int k = 0; k < 32; k++) {
      float4 av = *(const float4*)&atile[nL][k << 2];
      float4 wvv = *(const float4*)&wv_sh[tL][k << 2];
      pr += av.x * wvv.x + av.y * wvv.y + av.z * wvv.z + av.w * wvv.w;
    }
    float dt = pr + bv_sh[tL];
    int gn = st + n0 + nL;
    if (nL < nv) {
      if (USE_PREV_B) dt += b[gn * T_CAPS + tL];
      b[gn * T_CAPS + tL] = dt;
    }
    dtsh[nL][tL] = dt;
    __syncthreads();
    // softmax across t for this thread's node
    float cval = 0.f;
    if (nL < nv) {
      float m = dtsh[nL][0];
#pragma unroll
      for (int t = 1; t < T_CAPS; t++) m = fmaxf(m, dtsh[nL][t]);
      float Z = 0.f;
#pragma unroll
      for (int t = 0; t < T_CAPS; t++) Z += __expf(dtsh[nL][t] - m);
      cval = __expf(dt - m) / Z;
    }
    csh[nL][tL] = cval;
    csl += cval;
    __syncthreads();
    // accumulate: thread (tL, d4) over the tile's nodes
    for (int nj = 0; nj < nv; nj++) {
      float cj = csh[nj][tL];
      float4 av = *(const float4*)&atile[nj][d4];
      acc.x += cj * av.x;
      acc.y += cj * av.y;
      acc.z += cj * av.z;
      acc.w += cj * av.w;
    }
  }
  __syncthreads();
  dtsh[nL][tL] = csl;  // reuse as csum-reduction scratch
  __syncthreads();
  if (tid < T_CAPS) {
    float s = 0.f;
#pragma unroll 8
    for (int n = 0; n < 32; n++) s += dtsh[n][tid];
    csum[g * T_CAPS + tid] = s;
  }
  *(float4*)&ac[(g * T_CAPS + tL) * D_DIM + d4] = acc;
}

extern "C" void kernel_launch(void* const* d_in, const int* in_sizes, int n_in, void* d_out,
                              int out_size, void* d_ws, size_t ws_size, hipStream_t stream) {
  const float* x = (const float*)d_in[0];
  const float* ew = (const float*)d_in[1];
  const float* gamma = (const float*)d_in[2];
  const float* beta = (const float*)d_in[3];
  const float* W = (const float*)d_in[4];
  const float* bias = (const float*)d_in[5];
  const int* eidx = (const int*)d_in[6];
  const int* batch = (const int*)d_in[7];
  float* out = (float*)d_out;
  float* w = (float*)d_ws;

  const int* row = eidx;
  const int* col = eidx + N_EDGES;

  // --- zeroed region (single memset): colsum, colsq, deg | cnt, cnt_in, cursor ---
  float* colsum = w;
  float* colsq = w + 128;
  float* deg = w + 256;
  int* cnt = (int*)(w + 256 + N_NODES);
  int* cnt_in = cnt + N_GRAPHS;
  int* cursor = cnt_in + N_NODES;
  size_t zero_words = (size_t)(256 + N_NODES) + (N_GRAPHS + 2 * N_NODES);
  // --- rest ---
  float* scale = (float*)(cursor + N_NODES);
  float* shift = scale + 128;
  float* dis = shift + 128;
  int* start = (int*)(dis + N_NODES);
  int* node_start = start + N_GRAPHS;
  int* bsum = node_start + N_NODES;
  int* boff = bsum + 256;
  int2* csr = (int2*)(boff + 256);
  float* agg = (float*)(csr + N_EDGES);
  float* b = agg + (size_t)N_NODES * D_DIM;
  float* aggsum = b + (size_t)N_NODES * T_CAPS;
  float* xsum = aggsum + N_GRAPHS * D_DIM;
  float* wv = xsum + N_GRAPHS * D_DIM;
  float* bv = wv + N_GRAPHS * T_CAPS * D_DIM;
  float* ac = bv + N_GRAPHS * T_CAPS;
  float* csum = ac + N_GRAPHS * T_CAPS * D_DIM;

  hipMemsetAsync(w, 0, zero_words * sizeof(float), stream);

  bn_stats<<<512, 256, 0, stream>>>(x, colsum, colsq);
  hist_cnt<<<N_NODES / 256, 256, 0, stream>>>(batch, cnt);
  edge_hist<<<N_EDGES / 256, 256, 0, stream>>>(col, ew, deg, cnt_in);
  finalize_bn<<<1, 128, 0, stream>>>(colsum, colsq, gamma, beta, scale, shift);
  scan_cnt<<<1, N_GRAPHS, 0, stream>>>(cnt, start);
  scan_part<<<200, 256, 0, stream>>>(cnt_in, bsum);
  scan_off<<<1, 256, 0, stream>>>(bsum, boff);
  scan_fin<<<200, 256, 0, stream>>>(cnt_in, boff, deg, node_start, dis);
  fill_csr<<<N_EDGES / 256, 256, 0, stream>>>(row, col, ew, dis, node_start, cursor, csr);
  node_gather<<<N_NODES / 4, 256, 0, stream>>>(x, scale, shift, dis, node_start, cnt_in, csr,
                                               agg);
  graph_sums<<<N_GRAPHS, 256, 0, stream>>>(agg, x, scale, shift, start, cnt, aggsum, xsum);

  // routing iter 1 (c uniform = 1/8; node_deg init cancels in softmax)
  capsule_step<1><<<N_GRAPHS * T_CAPS, 128, 0, stream>>>(W, bias, aggsum, ac, csum, cnt, xsum,
                                                         wv, bv, out);
  node_pass2<0><<<N_GRAPHS, 256, 0, stream>>>(agg, start, cnt, wv, bv, b, ac, csum);
  // routing iter 2
  capsule_step<2><<<N_GRAPHS * T_CAPS, 128, 0, stream>>>(W, bias, aggsum, ac, csum, cnt, xsum,
                                                         wv, bv, out);
  node_pass2<1><<<N_GRAPHS, 256, 0, stream>>>(agg, start, cnt, wv, bv, b, ac, csum);
  // final
  capsule_step<3><<<N_GRAPHS * T_CAPS, 128, 0, stream>>>(W, bias, aggsum, ac, csum, cnt, xsum,
                                                         wv, bv, out);
}

// Round 4
// 391.658 us; speedup vs baseline: 1.8369x; 1.1740x over previous
//
#include <hip/hip_runtime.h>
#include <math.h>

#define N_NODES 51200
#define N_EDGES 614400
#define N_GRAPHS 256
#define T_CAPS 8
#define D_DIM 128
#define BN_EPS 1e-5f

__device__ inline float waveReduceSum(float v) {
#pragma unroll
  for (int off = 1; off < 64; off <<= 1) v += __shfl_xor(v, off, 64);
  return v;
}

// ---- graph segment bounds from sorted batch: no atomics ----
__global__ void graph_bounds(const int* __restrict__ batch, int* __restrict__ start) {
  int n = blockIdx.x * 256 + threadIdx.x;
  int bn = batch[n];
  if (n == 0) {
    for (int g = 0; g <= bn; g++) start[g] = 0;
  } else {
    int bp = batch[n - 1];
    for (int g = bp + 1; g <= bn; g++) start[g] = n;
  }
  if (n == N_NODES - 1) {
    for (int g = bn + 1; g <= N_GRAPHS; g++) start[g] = N_NODES;
  }
}

__global__ void graph_cnt(const int* __restrict__ start, int* __restrict__ cnt) {
  int g = threadIdx.x;
  cnt[g] = start[g + 1] - start[g];
}

// ---- per-graph x row-sums and row-sumsq (single pass over x) ----
__global__ void xstats(const float* __restrict__ x, const int* __restrict__ start,
                       const int* __restrict__ cnt, float* __restrict__ rawxsum,
                       float* __restrict__ rawxsq) {
  int g = blockIdx.x;
  int d = threadIdx.x & 127, h = threadIdx.x >> 7;
  int st = start[g], c = cnt[g];
  float s = 0.f, s2 = 0.f;
  for (int n = st + h; n < st + c; n += 2) {
    float v = x[n * D_DIM + d];
    s += v;
    s2 += v * v;
  }
  __shared__ float ls[256], ls2[256];
  ls[threadIdx.x] = s;
  ls2[threadIdx.x] = s2;
  __syncthreads();
  if (h == 0) {
    rawxsum[g * D_DIM + d] = ls[d] + ls[d + 128];
    rawxsq[g * D_DIM + d] = ls2[d] + ls2[d + 128];
  }
}

__global__ void finalize_bn(const float* __restrict__ rawxsum, const float* __restrict__ rawxsq,
                            const float* __restrict__ gamma, const float* __restrict__ beta,
                            float* __restrict__ scale, float* __restrict__ shift) {
  int d = threadIdx.x;
  float s = 0.f, s2 = 0.f;
  for (int g = 0; g < N_GRAPHS; g++) {
    s += rawxsum[g * D_DIM + d];
    s2 += rawxsq[g * D_DIM + d];
  }
  float mu = s * (1.0f / N_NODES);
  float var = s2 * (1.0f / N_NODES) - mu * mu;
  float rstd = rsqrtf(var + BN_EPS);
  float sc = gamma[d] * rstd;
  scale[d] = sc;
  shift[d] = beta[d] - mu * sc;
}

// per-edge integer in-degree histogram (random cols -> low contention)
__global__ void edge_hist(const int* __restrict__ col, int* __restrict__ cnt_in) {
  int e = blockIdx.x * blockDim.x + threadIdx.x;
  if (e < N_EDGES) atomicAdd(&cnt_in[col[e]], 1);
}

// ---- 3-stage parallel scan of cnt_in (51200 = 200 x 256) ----
__global__ void scan_part(const int* __restrict__ cnt_in, int* __restrict__ bsum) {
  __shared__ int ls[256];
  int i = blockIdx.x * 256 + threadIdx.x;
  ls[threadIdx.x] = cnt_in[i];
  __syncthreads();
  for (int off = 128; off; off >>= 1) {
    if (threadIdx.x < off) ls[threadIdx.x] += ls[threadIdx.x + off];
    __syncthreads();
  }
  if (threadIdx.x == 0) bsum[blockIdx.x] = ls[0];
}

__global__ void scan_off(const int* __restrict__ bsum, int* __restrict__ boff) {
  __shared__ int ls[256];
  int t = threadIdx.x;
  int v0 = (t < 200) ? bsum[t] : 0;
  ls[t] = v0;
  __syncthreads();
  for (int off = 1; off < 256; off <<= 1) {
    int v = (t >= off) ? ls[t - off] : 0;
    __syncthreads();
    ls[t] += v;
    __syncthreads();
  }
  if (t < 200) boff[t] = ls[t] - v0;
}

__global__ void scan_fin(const int* __restrict__ cnt_in, const int* __restrict__ boff,
                         int* __restrict__ node_start) {
  __shared__ int ls[256];
  int t = threadIdx.x;
  int idx = blockIdx.x * 256 + t;
  int v = cnt_in[idx];
  ls[t] = v;
  __syncthreads();
  for (int off = 1; off < 256; off <<= 1) {
    int u = (t >= off) ? ls[t - off] : 0;
    __syncthreads();
    ls[t] += u;
    __syncthreads();
  }
  node_start[idx] = boff[blockIdx.x] + ls[t] - v;
}

// bucket edges by destination: csr[slot] = (src, raw ew) as one 8B record
__global__ void fill_csr(const int* __restrict__ row, const int* __restrict__ col,
                         const float* __restrict__ ew, const int* __restrict__ node_start,
                         int* __restrict__ cursor, int2* __restrict__ csr) {
  int e = blockIdx.x * blockDim.x + threadIdx.x;
  if (e < N_EDGES) {
    int c = col[e];
    int slot = node_start[c] + atomicAdd(&cursor[c], 1);
    csr[slot] = make_int2(row[e], __float_as_int(ew[e]));
  }
}

// weighted in-degree from CSR segment (no atomics), then dis = rsqrt(deg+1)
__global__ void node_deg_dis(const int2* __restrict__ csr, const int* __restrict__ node_start,
                             const int* __restrict__ cnt_in, float* __restrict__ dis) {
  int n = blockIdx.x * 4 + (threadIdx.x >> 6);
  int lane = threadIdx.x & 63;
  int st = node_start[n], c = cnt_in[n];
  float s = 0.f;
  for (int k = lane; k < c; k += 64) s += __int_as_float(csr[st + k].y);
  s = waveReduceSum(s);
  if (lane == 0) {
    float dv = s + 1.0f;  // + self-loop weight
    dis[n] = dv > 0.f ? rsqrtf(fmaxf(dv, 1e-12f)) : 0.f;
  }
}

// one wave per node: agg[n] = dis[n] * sum_e dis[src]*ew*xhat[src] + dis[n]^2 * xhat[n]
__global__ void node_gather(const float* __restrict__ x, const float* __restrict__ scale,
                            const float* __restrict__ shift, const float* __restrict__ dis,
                            const int* __restrict__ node_start, const int* __restrict__ cnt_in,
                            const int2* __restrict__ csr, float* __restrict__ agg) {
  int n = blockIdx.x * 4 + (threadIdx.x >> 6);
  int lane = threadIdx.x & 63;
  const float2* x2 = (const float2*)x;
  float2 scv = ((const float2*)scale)[lane];
  float2 shv = ((const float2*)shift)[lane];
  int st = node_start[n], c = cnt_in[n];
  float a0 = 0.f, a1 = 0.f;
  int j = 0;
  for (; j + 4 <= c; j += 4) {
    int2 e0 = csr[st + j], e1 = csr[st + j + 1], e2 = csr[st + j + 2], e3 = csr[st + j + 3];
    float2 v0 = x2[e0.x * 64 + lane];
    float2 v1 = x2[e1.x * 64 + lane];
    float2 v2 = x2[e2.x * 64 + lane];
    float2 v3 = x2[e3.x * 64 + lane];
    float w0 = dis[e0.x] * __int_as_float(e0.y), w1 = dis[e1.x] * __int_as_float(e1.y);
    float w2 = dis[e2.x] * __int_as_float(e2.y), w3 = dis[e3.x] * __int_as_float(e3.y);
    a0 += w0 * (v0.x * scv.x + shv.x) + w1 * (v1.x * scv.x + shv.x) +
          w2 * (v2.x * scv.x + shv.x) + w3 * (v3.x * scv.x + shv.x);
    a1 += w0 * (v0.y * scv.y + shv.y) + w1 * (v1.y * scv.y + shv.y) +
          w2 * (v2.y * scv.y + shv.y) + w3 * (v3.y * scv.y + shv.y);
  }
  for (; j < c; j++) {
    int2 e = csr[st + j];
    float2 v = x2[e.x * 64 + lane];
    float w = dis[e.x] * __int_as_float(e.y);
    a0 += w * (v.x * scv.x + shv.x);
    a1 += w * (v.y * scv.y + shv.y);
  }
  float di = dis[n];
  float2 xs = x2[n * 64 + lane];
  float2 o;
  o.x = di * a0 + di * di * (xs.x * scv.x + shv.x);
  o.y = di * a1 + di * di * (xs.y * scv.y + shv.y);
  ((float2*)agg)[n * 64 + lane] = o;
}

// per-graph: aggsum[g,:] = sum of agg rows
__global__ void agg_sums(const float* __restrict__ agg, const int* __restrict__ start,
                         const int* __restrict__ cnt, float* __restrict__ aggsum) {
  int g = blockIdx.x;
  int d = threadIdx.x & 127, h = threadIdx.x >> 7;
  int st = start[g], c = cnt[g];
  float sa = 0.f;
  for (int n = st + h; n < st + c; n += 2) sa += agg[n * D_DIM + d];
  __shared__ float la[256];
  la[threadIdx.x] = sa;
  __syncthreads();
  if (h == 0) aggsum[g * D_DIM + d] = la[d] + la[d + 128];
}

// Per (g,t): s = p@W[t] + coef*bias[t] [+ x_mean]; v=squash(s);
// MODE 1: p=aggsum, coef=cnt, s*=1/8 (uniform c). outputs wv,bv
// MODE 2: p=ac[g,t], coef=csum.            outputs wv,bv
// MODE 3: p=ac[g,t], coef=csum, + x_mean (reconstructed from rawxsum). outputs |v|
template <int MODE>
__global__ void capsule_step(const float* __restrict__ W, const float* __restrict__ bias,
                             const float* __restrict__ aggsum, const float* __restrict__ ac,
                             const float* __restrict__ csum, const int* __restrict__ cnt,
                             const float* __restrict__ rawxsum, const float* __restrict__ scale,
                             const float* __restrict__ shift, float* __restrict__ wv,
                             float* __restrict__ bv, float* __restrict__ out) {
  int g = blockIdx.x >> 3, t = blockIdx.x & 7;
  int o = threadIdx.x;
  __shared__ float p[D_DIM];
  __shared__ float vsh[D_DIM];
  __shared__ float wred[2];
  if (MODE == 1)
    p[o] = aggsum[g * D_DIM + o];
  else
    p[o] = ac[(g * T_CAPS + t) * D_DIM + o];
  __syncthreads();
  const float* Wt = W + t * D_DIM * D_DIM;
  float s = 0.f;
#pragma unroll 8
  for (int dd = 0; dd < D_DIM; dd++) s += p[dd] * Wt[dd * D_DIM + o];
  float bterm = (MODE == 1) ? (float)cnt[g] : csum[g * T_CAPS + t];
  s += bterm * bias[t * D_DIM + o];
  if (MODE == 1) s *= 0.125f;
  if (MODE == 3) {
    float cf = (float)cnt[g];
    float ic = 1.0f / fmaxf(cf, 1.0f);
    // x_mean[d] = (scale[d]*rowsum + cnt*shift[d]) / cnt
    s += (scale[o] * rawxsum[g * D_DIM + o] + cf * shift[o]) * ic;
  }
  float ws = waveReduceSum(s * s);
  if ((threadIdx.x & 63) == 0) wred[threadIdx.x >> 6] = ws;
  __syncthreads();
  float s2 = wred[0] + wred[1];
  float f = (s2 / (1.0f + s2)) * rsqrtf(s2 + 1e-16f);
  if (MODE == 3) {
    if (o == 0) out[g * T_CAPS + t] = sqrtf(f * f * s2 + 1e-16f);
    return;
  }
  float v = f * s;
  vsh[o] = v;
  float bw = waveReduceSum(bias[t * D_DIM + o] * v);
  __syncthreads();
  if ((threadIdx.x & 63) == 0) wred[threadIdx.x >> 6] = bw;
  __syncthreads();
  if (o == 0) bv[g * T_CAPS + t] = wred[0] + wred[1];
  float acc = 0.f;
#pragma unroll 8
  for (int oo = 0; oo < D_DIM; oo++) acc += Wt[o * D_DIM + oo] * vsh[oo];
  wv[(g * T_CAPS + t) * D_DIM + o] = acc;
}

// one block (256 thr) per graph: proj + b update + softmax + weighted accumulation.
template <int USE_PREV_B>
__global__ void __launch_bounds__(256) node_pass2(
    const float* __restrict__ agg, const int* __restrict__ start, const int* __restrict__ cnt,
    const float* __restrict__ wv, const float* __restrict__ bv, float* __restrict__ b,
    float* __restrict__ ac, float* __restrict__ csum) {
  int g = blockIdx.x;
  int tid = threadIdx.x;
  __shared__ float wv_sh[T_CAPS][D_DIM];
  __shared__ float bv_sh[T_CAPS];
  __shared__ float atile[32][132];
  __shared__ float dtsh[32][9];
  __shared__ float csh[32][9];

  for (int i = tid; i < T_CAPS * D_DIM; i += 256) wv_sh[0][i] = wv[g * T_CAPS * D_DIM + i];
  if (tid < T_CAPS) bv_sh[tid] = bv[g * T_CAPS + tid];

  int st = start[g], c = cnt[g];
  int nL = tid & 31, tL = tid >> 5;
  float4 acc = make_float4(0.f, 0.f, 0.f, 0.f);
  int d4 = nL << 2;
  float csl = 0.f;

  int ntiles = (c + 31) >> 5;
  for (int tile = 0; tile < ntiles; tile++) {
    int n0 = tile * 32;
    int nv = min(32, c - n0);
    __syncthreads();
    const float4* aggv = (const float4*)(agg + (size_t)(st + n0) * D_DIM);
    for (int i = tid; i < 32 * 32; i += 256) {
      float4 v = (i < nv * 32) ? aggv[i] : make_float4(0.f, 0.f, 0.f, 0.f);
      *(float4*)&atile[i >> 5][(i & 31) << 2] = v;
    }
    __syncthreads();
    float pr = 0.f;
#pragma unroll 8
    for (int k = 0; k < 32; k++) {
      float4 av = *(const float4*)&atile[nL][k << 2];
      float4 wvv = *(const float4*)&wv_sh[tL][k << 2];
      pr += av.x * wvv.x + av.y * wvv.y + av.z * wvv.z + av.w * wvv.w;
    }
    float dt = pr + bv_sh[tL];
    int gn = st + n0 + nL;
    if (nL < nv) {
      if (USE_PREV_B) dt += b[gn * T_CAPS + tL];
      b[gn * T_CAPS + tL] = dt;
    }
    dtsh[nL][tL] = dt;
    __syncthreads();
    float cval = 0.f;
    if (nL < nv) {
      float m = dtsh[nL][0];
#pragma unroll
      for (int t = 1; t < T_CAPS; t++) m = fmaxf(m, dtsh[nL][t]);
      float Z = 0.f;
#pragma unroll
      for (int t = 0; t < T_CAPS; t++) Z += __expf(dtsh[nL][t] - m);
      cval = __expf(dt - m) / Z;
    }
    csh[nL][tL] = cval;
    csl += cval;
    __syncthreads();
    for (int nj = 0; nj < nv; nj++) {
      float cj = csh[nj][tL];
      float4 av = *(const float4*)&atile[nj][d4];
      acc.x += cj * av.x;
      acc.y += cj * av.y;
      acc.z += cj * av.z;
      acc.w += cj * av.w;
    }
  }
  __syncthreads();
  dtsh[nL][tL] = csl;
  __syncthreads();
  if (tid < T_CAPS) {
    float s = 0.f;
#pragma unroll 8
    for (int n = 0; n < 32; n++) s += dtsh[n][tid];
    csum[g * T_CAPS + tid] = s;
  }
  *(float4*)&ac[(g * T_CAPS + tL) * D_DIM + d4] = acc;
}

extern "C" void kernel_launch(void* const* d_in, const int* in_sizes, int n_in, void* d_out,
                              int out_size, void* d_ws, size_t ws_size, hipStream_t stream) {
  const float* x = (const float*)d_in[0];
  const float* ew = (const float*)d_in[1];
  const float* gamma = (const float*)d_in[2];
  const float* beta = (const float*)d_in[3];
  const float* W = (const float*)d_in[4];
  const float* bias = (const float*)d_in[5];
  const int* eidx = (const int*)d_in[6];
  const int* batch = (const int*)d_in[7];
  float* out = (float*)d_out;
  float* w = (float*)d_ws;

  const int* row = eidx;
  const int* col = eidx + N_EDGES;

  // --- zeroed region: cnt_in, cursor ---
  int* cnt_in = (int*)w;                  // N
  int* cursor = cnt_in + N_NODES;         // N
  // --- rest (fully overwritten before use) ---
  int* start = cursor + N_NODES;          // G+2 (pad keeps csr 8B-aligned)
  int* cnt = start + (N_GRAPHS + 2);      // G
  int* node_start = cnt + N_GRAPHS;       // N
  int* bsum = node_start + N_NODES;       // 256
  int* boff = bsum + 256;                 // 256
  float* scale = (float*)(boff + 256);    // 128
  float* shift = scale + 128;             // 128
  float* dis = shift + 128;               // N
  float* rawxsum = dis + N_NODES;         // G*128
  float* rawxsq = rawxsum + N_GRAPHS * D_DIM;  // G*128
  int2* csr = (int2*)(rawxsq + N_GRAPHS * D_DIM);  // E
  float* agg = (float*)(csr + N_EDGES);   // N*128
  float* b = agg + (size_t)N_NODES * D_DIM;
  float* aggsum = b + (size_t)N_NODES * T_CAPS;
  float* wv = aggsum + N_GRAPHS * D_DIM;
  float* bv = wv + N_GRAPHS * T_CAPS * D_DIM;
  float* ac = bv + N_GRAPHS * T_CAPS;
  float* csum = ac + N_GRAPHS * T_CAPS * D_DIM;

  hipMemsetAsync(cnt_in, 0, 2 * N_NODES * sizeof(int), stream);

  graph_bounds<<<N_NODES / 256, 256, 0, stream>>>(batch, start);
  graph_cnt<<<1, N_GRAPHS, 0, stream>>>(start, cnt);
  xstats<<<N_GRAPHS, 256, 0, stream>>>(x, start, cnt, rawxsum, rawxsq);
  finalize_bn<<<1, 128, 0, stream>>>(rawxsum, rawxsq, gamma, beta, scale, shift);
  edge_hist<<<N_EDGES / 256, 256, 0, stream>>>(col, cnt_in);
  scan_part<<<200, 256, 0, stream>>>(cnt_in, bsum);
  scan_off<<<1, 256, 0, stream>>>(bsum, boff);
  scan_fin<<<200, 256, 0, stream>>>(cnt_in, boff, node_start);
  fill_csr<<<N_EDGES / 256, 256, 0, stream>>>(row, col, ew, node_start, cursor, csr);
  node_deg_dis<<<N_NODES / 4, 256, 0, stream>>>(csr, node_start, cnt_in, dis);
  node_gather<<<N_NODES / 4, 256, 0, stream>>>(x, scale, shift, dis, node_start, cnt_in, csr,
                                               agg);
  agg_sums<<<N_GRAPHS, 256, 0, stream>>>(agg, start, cnt, aggsum);

  // routing iter 1 (c uniform = 1/8; node_deg init cancels in softmax)
  capsule_step<1><<<N_GRAPHS * T_CAPS, 128, 0, stream>>>(W, bias, aggsum, ac, csum, cnt,
                                                         rawxsum, scale, shift, wv, bv, out);
  node_pass2<0><<<N_GRAPHS, 256, 0, stream>>>(agg, start, cnt, wv, bv, b, ac, csum);
  // routing iter 2
  capsule_step<2><<<N_GRAPHS * T_CAPS, 128, 0, stream>>>(W, bias, aggsum, ac, csum, cnt,
                                                         rawxsum, scale, shift, wv, bv, out);
  node_pass2<1><<<N_GRAPHS, 256, 0, stream>>>(agg, start, cnt, wv, bv, b, ac, csum);
  // final
  capsule_step<3><<<N_GRAPHS * T_CAPS, 128, 0, stream>>>(W, bias, aggsum, ac, csum, cnt,
                                                         rawxsum, scale, shift, wv, bv, out);
}

// Round 5
// 308.750 us; speedup vs baseline: 2.3302x; 1.2685x over previous
//
#include <hip/hip_runtime.h>
#include <hip/hip_bf16.h>
#include <math.h>

#define N_NODES 51200
#define N_EDGES 614400
#define N_GRAPHS 256
#define T_CAPS 8
#define D_DIM 128
#define BN_EPS 1e-5f

__device__ inline float waveReduceSum(float v) {
#pragma unroll
  for (int off = 1; off < 64; off <<= 1) v += __shfl_xor(v, off, 64);
  return v;
}

// ---- graph segment bounds from sorted batch: no atomics ----
__global__ void graph_bounds(const int* __restrict__ batch, int* __restrict__ start) {
  int n = blockIdx.x * 256 + threadIdx.x;
  int bn = batch[n];
  if (n == 0) {
    for (int g = 0; g <= bn; g++) start[g] = 0;
  } else {
    int bp = batch[n - 1];
    for (int g = bp + 1; g <= bn; g++) start[g] = n;
  }
  if (n == N_NODES - 1) {
    for (int g = bn + 1; g <= N_GRAPHS; g++) start[g] = N_NODES;
  }
}

// ---- per-graph x row-sums and row-sumsq (single pass over x) ----
__global__ void __launch_bounds__(512) xstats(const float* __restrict__ x,
                                              const int* __restrict__ start,
                                              float* __restrict__ rawxsum,
                                              float* __restrict__ rawxsq) {
  int g = blockIdx.x;
  int tid = threadIdx.x;
  int d = tid & 127, h = tid >> 7;
  int st = start[g], en = start[g + 1];
  float s = 0.f, s2 = 0.f;
  for (int n = st + h; n < en; n += 4) {
    float v = x[n * D_DIM + d];
    s += v;
    s2 += v * v;
  }
  __shared__ float ls[512], ls2[512];
  ls[tid] = s;
  ls2[tid] = s2;
  __syncthreads();
  if (h == 0) {
    rawxsum[g * D_DIM + d] = ls[d] + ls[d + 128] + ls[d + 256] + ls[d + 384];
    rawxsq[g * D_DIM + d] = ls2[d] + ls2[d + 128] + ls2[d + 256] + ls2[d + 384];
  }
}

// parallel: one block per feature d, 256 threads over graphs
__global__ void finalize_bn(const float* __restrict__ rawxsum, const float* __restrict__ rawxsq,
                            const float* __restrict__ gamma, const float* __restrict__ beta,
                            float* __restrict__ scale, float* __restrict__ shift) {
  int d = blockIdx.x;
  int g = threadIdx.x;
  __shared__ float ls[256], ls2[256];
  ls[g] = rawxsum[g * D_DIM + d];
  ls2[g] = rawxsq[g * D_DIM + d];
  __syncthreads();
  for (int off = 128; off; off >>= 1) {
    if (g < off) {
      ls[g] += ls[g + off];
      ls2[g] += ls2[g + off];
    }
    __syncthreads();
  }
  if (g == 0) {
    float mu = ls[0] * (1.0f / N_NODES);
    float var = ls2[0] * (1.0f / N_NODES) - mu * mu;
    float rstd = rsqrtf(var + BN_EPS);
    float sc = gamma[d] * rstd;
    scale[d] = sc;
    shift[d] = beta[d] - mu * sc;
  }
}

__global__ void edge_hist(const int* __restrict__ col, int* __restrict__ cnt_in) {
  int e = blockIdx.x * blockDim.x + threadIdx.x;
  if (e < N_EDGES) atomicAdd(&cnt_in[col[e]], 1);
}

// ---- 3-stage parallel scan of cnt_in (51200 = 200 x 256) ----
__global__ void scan_part(const int* __restrict__ cnt_in, int* __restrict__ bsum) {
  __shared__ int ls[256];
  int i = blockIdx.x * 256 + threadIdx.x;
  ls[threadIdx.x] = cnt_in[i];
  __syncthreads();
  for (int off = 128; off; off >>= 1) {
    if (threadIdx.x < off) ls[threadIdx.x] += ls[threadIdx.x + off];
    __syncthreads();
  }
  if (threadIdx.x == 0) bsum[blockIdx.x] = ls[0];
}

__global__ void scan_off(const int* __restrict__ bsum, int* __restrict__ boff) {
  __shared__ int ls[256];
  int t = threadIdx.x;
  int v0 = (t < 200) ? bsum[t] : 0;
  ls[t] = v0;
  __syncthreads();
  for (int off = 1; off < 256; off <<= 1) {
    int v = (t >= off) ? ls[t - off] : 0;
    __syncthreads();
    ls[t] += v;
    __syncthreads();
  }
  if (t < 200) boff[t] = ls[t] - v0;
}

__global__ void scan_fin(const int* __restrict__ cnt_in, const int* __restrict__ boff,
                         int* __restrict__ node_start) {
  __shared__ int ls[256];
  int t = threadIdx.x;
  int idx = blockIdx.x * 256 + t;
  int v = cnt_in[idx];
  ls[t] = v;
  __syncthreads();
  for (int off = 1; off < 256; off <<= 1) {
    int u = (t >= off) ? ls[t - off] : 0;
    __syncthreads();
    ls[t] += u;
    __syncthreads();
  }
  node_start[idx] = boff[blockIdx.x] + ls[t] - v;
}

// bucket edges by destination: csr[slot] = (src, raw ew)
__global__ void fill_csr(const int* __restrict__ row, const int* __restrict__ col,
                         const float* __restrict__ ew, const int* __restrict__ node_start,
                         int* __restrict__ cursor, int2* __restrict__ csr) {
  int e = blockIdx.x * blockDim.x + threadIdx.x;
  if (e < N_EDGES) {
    int c = col[e];
    int slot = node_start[c] + atomicAdd(&cursor[c], 1);
    csr[slot] = make_int2(row[e], __float_as_int(ew[e]));
  }
}

// one wave per node: deg from csr, dis=rsqrt(deg+1), y = bf16(dis * xhat)
__global__ void make_y(const float* __restrict__ x, const float* __restrict__ scale,
                       const float* __restrict__ shift, const int* __restrict__ node_start,
                       const int* __restrict__ cnt_in, const int2* __restrict__ csr,
                       float* __restrict__ dis, __hip_bfloat162* __restrict__ y) {
  int n = blockIdx.x * 4 + (threadIdx.x >> 6);
  int lane = threadIdx.x & 63;
  int st = node_start[n], c = cnt_in[n];
  float s = 0.f;
  for (int k = lane; k < c; k += 64) s += __int_as_float(csr[st + k].y);
  s = waveReduceSum(s);
  float dv = s + 1.0f;  // + self-loop weight
  float dn = dv > 0.f ? rsqrtf(fmaxf(dv, 1e-12f)) : 0.f;
  if (lane == 0) dis[n] = dn;
  float2 scv = ((const float2*)scale)[lane];
  float2 shv = ((const float2*)shift)[lane];
  float2 xv = ((const float2*)x)[n * 64 + lane];
  float2 yv;
  yv.x = dn * (xv.x * scv.x + shv.x);
  yv.y = dn * (xv.y * scv.y + shv.y);
  y[n * 64 + lane] = __float22bfloat162_rn(yv);
}

// one wave per node: agg[n] = dis[n] * (y[n] + sum_e ew_e * y[src_e])
__global__ void node_gather(const __hip_bfloat162* __restrict__ y, const float* __restrict__ dis,
                            const int* __restrict__ node_start, const int* __restrict__ cnt_in,
                            const int2* __restrict__ csr, float* __restrict__ agg) {
  int n = blockIdx.x * 4 + (threadIdx.x >> 6);
  int lane = threadIdx.x & 63;
  int st = node_start[n], c = cnt_in[n];
  float2 a = __bfloat1622float2(y[n * 64 + lane]);  // self term
  int j = 0;
  for (; j + 4 <= c; j += 4) {
    int2 e0 = csr[st + j], e1 = csr[st + j + 1], e2 = csr[st + j + 2], e3 = csr[st + j + 3];
    float2 v0 = __bfloat1622float2(y[e0.x * 64 + lane]);
    float2 v1 = __bfloat1622float2(y[e1.x * 64 + lane]);
    float2 v2 = __bfloat1622float2(y[e2.x * 64 + lane]);
    float2 v3 = __bfloat1622float2(y[e3.x * 64 + lane]);
    float w0 = __int_as_float(e0.y), w1 = __int_as_float(e1.y);
    float w2 = __int_as_float(e2.y), w3 = __int_as_float(e3.y);
    a.x += w0 * v0.x + w1 * v1.x + w2 * v2.x + w3 * v3.x;
    a.y += w0 * v0.y + w1 * v1.y + w2 * v2.y + w3 * v3.y;
  }
  for (; j < c; j++) {
    int2 e = csr[st + j];
    float2 v = __bfloat1622float2(y[e.x * 64 + lane]);
    float w = __int_as_float(e.y);
    a.x += w * v.x;
    a.y += w * v.y;
  }
  float dn = dis[n];
  a.x *= dn;
  a.y *= dn;
  ((float2*)agg)[n * 64 + lane] = a;
}

// WT[t][oo][o] = W[t][o][oo]
__global__ void build_wt(const float* __restrict__ W, float* __restrict__ WT) {
  int i = blockIdx.x * 256 + threadIdx.x;  // 131072 total
  int t = i >> 14, r = i & 16383;
  int oo = r >> 7, o = r & 127;
  WT[i] = W[(t * D_DIM + o) * D_DIM + oo];
}

// ---- the whole routing phase: one block (512 thr) per graph ----
__global__ void __launch_bounds__(512) routing_fused(
    const float* __restrict__ agg, const int* __restrict__ start, const float* __restrict__ W,
    const float* __restrict__ WT, const float* __restrict__ bias,
    const float* __restrict__ rawxsum, const float* __restrict__ scale,
    const float* __restrict__ shift, float* __restrict__ b, float* __restrict__ out) {
  int g = blockIdx.x;
  int tid = threadIdx.x;
  int st = start[g], c = start[g + 1] - st;

  __shared__ float atile[64][132];  // agg tile; also reduction scratch
  __shared__ float ac_sh[T_CAPS][132];
  __shared__ float s_sh[T_CAPS][132];  // s, then v (scaled in place)
  __shared__ float wv_sh[T_CAPS][132];
  __shared__ float dtsh[64][9];
  __shared__ float csh[64][9];
  __shared__ float csum_sh[T_CAPS], bv_sh[T_CAPS], f_sh[T_CAPS], s2_sh[T_CAPS];

  float* flat = &atile[0][0];

  // Phase 0: aggsum/8 -> ac_sh (uniform softmax c=1/8), csum = c/8
  {
    int d = tid & 127, h = tid >> 7;
    float sa = 0.f;
    for (int n = st + h; n < st + c; n += 4) sa += agg[n * D_DIM + d];
    flat[h * 128 + d] = sa;
    __syncthreads();
    if (h == 0) {
      float v = (flat[d] + flat[128 + d] + flat[256 + d] + flat[384 + d]) * 0.125f;
#pragma unroll
      for (int t = 0; t < T_CAPS; t++) ac_sh[t][d] = v;
    }
    if (tid < T_CAPS) csum_sh[tid] = 0.125f * (float)c;
  }
  __syncthreads();

  int t = tid >> 6, oh = tid & 63;                            // GEMV: wave t, lane oh
  int nL = tid >> 3, tL = tid & 7;                            // proj/softmax layout
  int hh = tid >> 8, at = (tid >> 5) & 7, d4 = (tid & 31) << 2;  // accum layout

  for (int iter = 0; iter < 3; iter++) {
    // GEMV1: s[t][o] = sum_dd ac_sh[t][dd]*W[t][dd][o] + csum*bias (+x_mean on last)
    {
      const float* Wt = W + t * D_DIM * D_DIM;
      float sA = 0.f, sB = 0.f;
#pragma unroll 4
      for (int dd = 0; dd < D_DIM; dd++) {
        float p = ac_sh[t][dd];
        sA += p * Wt[dd * D_DIM + oh];
        sB += p * Wt[dd * D_DIM + 64 + oh];
      }
      float cs = csum_sh[t];
      sA += cs * bias[t * D_DIM + oh];
      sB += cs * bias[t * D_DIM + 64 + oh];
      if (iter == 2) {
        float cf = (float)c;
        float ic = 1.0f / fmaxf(cf, 1.0f);
        sA += (scale[oh] * rawxsum[g * D_DIM + oh] + cf * shift[oh]) * ic;
        sB += (scale[64 + oh] * rawxsum[g * D_DIM + 64 + oh] + cf * shift[64 + oh]) * ic;
      }
      s_sh[t][oh] = sA;
      s_sh[t][64 + oh] = sB;
      float w2 = waveReduceSum(sA * sA + sB * sB);
      if (oh == 0) s2_sh[t] = w2;
    }
    __syncthreads();
    if (tid < T_CAPS) {
      float s2 = s2_sh[tid];
      float f = (s2 / (1.0f + s2)) * rsqrtf(s2 + 1e-16f);
      f_sh[tid] = f;
      if (iter == 2) out[g * T_CAPS + tid] = sqrtf(f * f * s2 + 1e-16f);
    }
    __syncthreads();
    if (iter == 2) return;
    {  // s -> v in place
      float f = f_sh[t];
      s_sh[t][oh] *= f;
      s_sh[t][64 + oh] *= f;
    }
    __syncthreads();
    // GEMV2: wv[t][o] = sum_oo WT[t][oo][o]*v[oo]; bv = bias·v
    {
      const float* WTt = WT + t * D_DIM * D_DIM;
      float sA = 0.f, sB = 0.f;
#pragma unroll 4
      for (int oo = 0; oo < D_DIM; oo++) {
        float v = s_sh[t][oo];
        sA += v * WTt[oo * D_DIM + oh];
        sB += v * WTt[oo * D_DIM + 64 + oh];
      }
      wv_sh[t][oh] = sA;
      wv_sh[t][64 + oh] = sB;
      float bp = bias[t * D_DIM + oh] * s_sh[t][oh] +
                 bias[t * D_DIM + 64 + oh] * s_sh[t][64 + oh];
      bp = waveReduceSum(bp);
      if (oh == 0) bv_sh[t] = bp;
    }
    __syncthreads();
    // node pass over this graph's rows
    float4 acc = make_float4(0.f, 0.f, 0.f, 0.f);
    float csl = 0.f;
    int ntiles = (c + 63) >> 6;
    for (int tile = 0; tile < ntiles; tile++) {
      int n0 = tile << 6;
      int nv = min(64, c - n0);
      __syncthreads();
      const float4* aggv = (const float4*)(agg + (size_t)(st + n0) * D_DIM);
      for (int i = tid; i < 64 * 32; i += 512) {
        float4 v = (i < nv * 32) ? aggv[i] : make_float4(0.f, 0.f, 0.f, 0.f);
        *(float4*)&atile[i >> 5][(i & 31) << 2] = v;
      }
      __syncthreads();
      float pr = 0.f;
#pragma unroll 8
      for (int k = 0; k < 32; k++) {
        float4 av = *(const float4*)&atile[nL][k << 2];
        float4 wvv = *(const float4*)&wv_sh[tL][k << 2];
        pr += av.x * wvv.x + av.y * wvv.y + av.z * wvv.z + av.w * wvv.w;
      }
      float dt = pr + bv_sh[tL];
      int gn = st + n0 + nL;
      if (nL < nv) {
        if (iter == 1) dt += b[gn * T_CAPS + tL];
        b[gn * T_CAPS + tL] = dt;
      }
      dtsh[nL][tL] = dt;
      __syncthreads();
      float cval = 0.f;
      if (nL < nv) {
        float m = dtsh[nL][0];
#pragma unroll
        for (int q = 1; q < T_CAPS; q++) m = fmaxf(m, dtsh[nL][q]);
        float Z = 0.f;
#pragma unroll
        for (int q = 0; q < T_CAPS; q++) Z += __expf(dtsh[nL][q] - m);
        cval = __expf(dt - m) / Z;
      }
      csh[nL][tL] = cval;
      csl += cval;
      __syncthreads();
      for (int nj = hh; nj < nv; nj += 2) {
        float cj = csh[nj][at];
        float4 av = *(const float4*)&atile[nj][d4];
        acc.x += cj * av.x;
        acc.y += cj * av.y;
        acc.z += cj * av.z;
        acc.w += cj * av.w;
      }
    }
    __syncthreads();  // atile/dtsh free for merge scratch
    dtsh[nL][tL] = csl;
    int slot = at * 32 + (d4 >> 2);
    if (hh == 1) *(float4*)&flat[slot * 4] = acc;
    __syncthreads();
    if (hh == 0) {
      float4 o4 = *(const float4*)&flat[slot * 4];
      acc.x += o4.x;
      acc.y += o4.y;
      acc.z += o4.z;
      acc.w += o4.w;
      *(float4*)&ac_sh[at][d4] = acc;
    }
    if (tid < T_CAPS) {
      float ssum = 0.f;
#pragma unroll
      for (int q = 0; q < 64; q++) ssum += dtsh[q][tid];
      csum_sh[tid] = ssum;
    }
    __syncthreads();
  }
}

extern "C" void kernel_launch(void* const* d_in, const int* in_sizes, int n_in, void* d_out,
                              int out_size, void* d_ws, size_t ws_size, hipStream_t stream) {
  const float* x = (const float*)d_in[0];
  const float* ew = (const float*)d_in[1];
  const float* gamma = (const float*)d_in[2];
  const float* beta = (const float*)d_in[3];
  const float* W = (const float*)d_in[4];
  const float* bias = (const float*)d_in[5];
  const int* eidx = (const int*)d_in[6];
  const int* batch = (const int*)d_in[7];
  float* out = (float*)d_out;
  float* w = (float*)d_ws;

  const int* row = eidx;
  const int* col = eidx + N_EDGES;

  // --- zeroed: cnt_in, cursor ---
  int* cnt_in = (int*)w;                       // N
  int* cursor = cnt_in + N_NODES;              // N
  // --- rest (overwritten before use) ---
  int* start = cursor + N_NODES;               // 258 (even pad)
  int* node_start = start + 258;               // N
  int* bsum = node_start + N_NODES;            // 256
  int* boff = bsum + 256;                      // 256
  float* scale = (float*)(boff + 256);         // 128
  float* shift = scale + 128;                  // 128
  float* dis = shift + 128;                    // N
  float* rawxsum = dis + N_NODES;              // 256*128
  float* rawxsq = rawxsum + N_GRAPHS * D_DIM;  // 256*128
  float* WT = rawxsq + N_GRAPHS * D_DIM;       // 131072
  int2* csr = (int2*)(WT + T_CAPS * D_DIM * D_DIM);        // E
  __hip_bfloat162* y = (__hip_bfloat162*)(csr + N_EDGES);  // N*64
  float* agg = (float*)(y + (size_t)N_NODES * 64);         // N*128
  float* b = agg + (size_t)N_NODES * D_DIM;                // N*8

  hipMemsetAsync(cnt_in, 0, 2 * N_NODES * sizeof(int), stream);

  build_wt<<<512, 256, 0, stream>>>(W, WT);
  graph_bounds<<<N_NODES / 256, 256, 0, stream>>>(batch, start);
  xstats<<<N_GRAPHS, 512, 0, stream>>>(x, start, rawxsum, rawxsq);
  finalize_bn<<<D_DIM, 256, 0, stream>>>(rawxsum, rawxsq, gamma, beta, scale, shift);
  edge_hist<<<N_EDGES / 256, 256, 0, stream>>>(col, cnt_in);
  scan_part<<<200, 256, 0, stream>>>(cnt_in, bsum);
  scan_off<<<1, 256, 0, stream>>>(bsum, boff);
  scan_fin<<<200, 256, 0, stream>>>(cnt_in, boff, node_start);
  fill_csr<<<N_EDGES / 256, 256, 0, stream>>>(row, col, ew, node_start, cursor, csr);
  make_y<<<N_NODES / 4, 256, 0, stream>>>(x, scale, shift, node_start, cnt_in, csr, dis, y);
  node_gather<<<N_NODES / 4, 256, 0, stream>>>(y, dis, node_start, cnt_in, csr, agg);
  routing_fused<<<N_GRAPHS, 512, 0, stream>>>(agg, start, W, WT, bias, rawxsum, scale, shift,
                                              b, out);
}